// Round 1
// baseline (602.933 us; speedup 1.0000x reference)
//
#include <hip/hip_runtime.h>

#define Bn 65536
#define Tn 100
#define Cn 7

__device__ __forceinline__ float fast_rcp(float x) { return __builtin_amdgcn_rcpf(x); }
__device__ __forceinline__ float sig_f(float x) { return fast_rcp(1.f + __expf(-x)); }
// tanh(x) = 1 - 2/(e^{2x}+1): saturates cleanly to +/-1, no inf/inf NaN
__device__ __forceinline__ float tanh_f(float x) { return 1.f - 2.f * fast_rcp(__expf(2.f * x) + 1.f); }

// ---------------- K0: transpose fc1_w (64,400) -> fc1_wt (400,64) ----------------
__global__ void fc1t_kernel(const float* __restrict__ fc1_w, float* __restrict__ fc1_wt) {
    int idx = blockIdx.x * 256 + threadIdx.x;  // 25600 total
    if (idx < 400 * 64) {
        int col = idx >> 6;   // 0..399
        int k = idx & 63;     // 0..63
        fc1_wt[idx] = fc1_w[k * 400 + col];
    }
}

// ---------------- K1: bidirectional LSTM layer 0 ----------------
// grid 512 x 256 threads: 128 samples/block, tid<128 = forward dir, tid>=128 = reverse dir.
// x (B,T,C) staged through LDS chunk buffers (10 timesteps each) with coalesced loads.
// h1 written as [T][4][B]  (planes 0,1 = fwd h ; 2,3 = rev h) -> coalesced for layer 1.
__global__ __launch_bounds__(256, 2) void l0_kernel(
    const float* __restrict__ x,
    const float* __restrict__ wih_f, const float* __restrict__ whh_f,
    const float* __restrict__ bih_f, const float* __restrict__ bhh_f,
    const float* __restrict__ wih_r, const float* __restrict__ whh_r,
    const float* __restrict__ bih_r, const float* __restrict__ bhh_r,
    float* __restrict__ h1)
{
    __shared__ float xsF[128][71];  // 70 floats (10 steps x 7) + 1 pad (stride 71: 2-way-free banks)
    __shared__ float xsR[128][71];

    const int tid = threadIdx.x;
    const int rev = tid >> 7;       // wave-uniform (waves 0,1 fwd; 2,3 rev)
    const int s   = tid & 127;
    const int b   = blockIdx.x * 128 + s;

    const float* wih = rev ? wih_r : wih_f;
    const float* whh = rev ? whh_r : whh_f;
    const float* bih = rev ? bih_r : bih_f;
    const float* bhh = rev ? bhh_r : bhh_f;

    float wi[56], wh[16], bias[8];
#pragma unroll
    for (int k = 0; k < 56; ++k) wi[k] = wih[k];
#pragma unroll
    for (int k = 0; k < 16; ++k) wh[k] = whh[k];
#pragma unroll
    for (int k = 0; k < 8; ++k) bias[k] = bih[k] + bhh[k];

    float h0 = 0.f, h1v = 0.f, c0 = 0.f, c1 = 0.f;
    float (*xs)[71] = rev ? xsR : xsF;

    for (int ch = 0; ch < 10; ++ch) {
        __syncthreads();  // protect previous chunk's readers
        {
            const int t0F = ch * 10;
            const int t0R = 90 - ch * 10;
            // cooperative coalesced load of both chunk buffers (35 iters each)
            for (int f = tid; f < 128 * 70; f += 256) {
                int ss = f / 70;
                int r  = f - ss * 70;
                size_t rowbase = (size_t)(blockIdx.x * 128 + ss) * (Tn * Cn);
                xsF[ss][r] = x[rowbase + t0F * Cn + r];
                xsR[ss][r] = x[rowbase + t0R * Cn + r];
            }
        }
        __syncthreads();

        const int t0 = rev ? (90 - ch * 10) : (ch * 10);
        for (int tt = 0; tt < 10; ++tt) {
            const int rr = rev ? (9 - tt) : tt;   // row within chunk
            const int t  = t0 + rr;
            const int ro = rr * Cn;

            float g[8];
#pragma unroll
            for (int k = 0; k < 8; ++k) g[k] = bias[k];
#pragma unroll
            for (int c = 0; c < 7; ++c) {
                const float xv = xs[s][ro + c];
#pragma unroll
                for (int k = 0; k < 8; ++k) g[k] = fmaf(wi[k * 7 + c], xv, g[k]);
            }
#pragma unroll
            for (int k = 0; k < 8; ++k)
                g[k] = fmaf(wh[k * 2], h0, fmaf(wh[k * 2 + 1], h1v, g[k]));

            // gate order per jnp.split: i=g[0:2], f=g[2:4], g~=g[4:6], o=g[6:8]
            const float i0 = sig_f(g[0]), i1 = sig_f(g[1]);
            const float f0 = sig_f(g[2]), f1 = sig_f(g[3]);
            const float q0 = tanh_f(g[4]), q1 = tanh_f(g[5]);
            const float o0 = sig_f(g[6]), o1 = sig_f(g[7]);
            c0 = fmaf(f0, c0, i0 * q0);
            c1 = fmaf(f1, c1, i1 * q1);
            h0  = o0 * tanh_f(c0);
            h1v = o1 * tanh_f(c1);

            const size_t ob = ((size_t)t * 4 + rev * 2) * Bn + b;
            h1[ob]      = h0;
            h1[ob + Bn] = h1v;
        }
    }
}

// ---------------- K2: bidirectional LSTM layer 1 + fused ReLU/fc1/ReLU/fc2 ----------------
// grid 512 x 256: 128 samples/block x {fwd,rev}. Each thread accumulates its direction's
// fc1 contribution on the fly (h2/hb never materialized). Partial accs merged via LDS.
__global__ __launch_bounds__(256, 2) void l1fc_kernel(
    const float* __restrict__ h1,
    const float* __restrict__ wih_f, const float* __restrict__ whh_f,
    const float* __restrict__ bih_f, const float* __restrict__ bhh_f,
    const float* __restrict__ wih_r, const float* __restrict__ whh_r,
    const float* __restrict__ bih_r, const float* __restrict__ bhh_r,
    const float* __restrict__ fc1_wt,   // [400][64]
    const float* __restrict__ fc1_b,
    const float* __restrict__ fc2_w,    // [20][64]
    const float* __restrict__ fc2_b,
    float* __restrict__ out)            // [B][20]
{
    __shared__ float xch[128][65];      // acc exchange (stride 65: conflict-free), reused for out repack

    const int tid = threadIdx.x;
    const int rev = tid >> 7;
    const int s   = tid & 127;
    const int b   = blockIdx.x * 128 + s;

    const float* wih = rev ? wih_r : wih_f;
    const float* whh = rev ? whh_r : whh_f;
    const float* bih = rev ? bih_r : bih_f;
    const float* bhh = rev ? bhh_r : bhh_f;

    float wi[32], wh[16], bias[8];
#pragma unroll
    for (int k = 0; k < 32; ++k) wi[k] = wih[k];
#pragma unroll
    for (int k = 0; k < 16; ++k) wh[k] = whh[k];
#pragma unroll
    for (int k = 0; k < 8; ++k) bias[k] = bih[k] + bhh[k];

    float acc[64];
#pragma unroll
    for (int k = 0; k < 64; ++k) acc[k] = 0.f;

    float h0 = 0.f, h1v = 0.f, c0 = 0.f, c1 = 0.f;

    // software prefetch of step-0 inputs
    {
        const int t = rev ? 99 : 0;
        const size_t ib = (size_t)t * 4 * Bn + b;
        float a0 = h1[ib], a1 = h1[ib + Bn], a2 = h1[ib + 2 * Bn], a3 = h1[ib + 3 * Bn];

        for (int step = 0; step < 100; ++step) {
            const int tcur = rev ? (99 - step) : step;
            const int tnxt = rev ? (step < 99 ? 98 - step : 99)
                                 : (step < 99 ? step + 1 : 0);
            const size_t nb = (size_t)tnxt * 4 * Bn + b;
            const float n0 = h1[nb], n1 = h1[nb + Bn], n2 = h1[nb + 2 * Bn], n3 = h1[nb + 3 * Bn];

            float g[8];
#pragma unroll
            for (int k = 0; k < 8; ++k) {
                g[k] = bias[k];
                g[k] = fmaf(wi[k * 4 + 0], a0, g[k]);
                g[k] = fmaf(wi[k * 4 + 1], a1, g[k]);
                g[k] = fmaf(wi[k * 4 + 2], a2, g[k]);
                g[k] = fmaf(wi[k * 4 + 3], a3, g[k]);
                g[k] = fmaf(wh[k * 2], h0, fmaf(wh[k * 2 + 1], h1v, g[k]));
            }
            const float i0 = sig_f(g[0]), i1 = sig_f(g[1]);
            const float f0 = sig_f(g[2]), f1 = sig_f(g[3]);
            const float q0 = tanh_f(g[4]), q1 = tanh_f(g[5]);
            const float o0 = sig_f(g[6]), o1 = sig_f(g[7]);
            c0 = fmaf(f0, c0, i0 * q0);
            c1 = fmaf(f1, c1, i1 * q1);
            h0  = o0 * tanh_f(c0);
            h1v = o1 * tanh_f(c1);

            // fused fc1: fwd thread owns columns t*4+{0,1}, rev thread t*4+{2,3}
            const float v0 = fmaxf(h0, 0.f);
            const float v1 = fmaxf(h1v, 0.f);
            const float* wc = fc1_wt + ((size_t)tcur * 4 + rev * 2) * 64;  // uniform per wave
#pragma unroll
            for (int k = 0; k < 64; ++k)
                acc[k] = fmaf(wc[k], v0, fmaf(wc[64 + k], v1, acc[k]));

            a0 = n0; a1 = n1; a2 = n2; a3 = n3;
        }
    }

    if (rev) {
#pragma unroll
        for (int k = 0; k < 64; ++k) xch[s][k] = acc[k];
    }
    __syncthreads();

    float y[20];
    if (!rev) {
        float z[64];
#pragma unroll
        for (int k = 0; k < 64; ++k)
            z[k] = fmaxf(acc[k] + xch[s][k] + fc1_b[k], 0.f);
#pragma unroll
        for (int o = 0; o < 20; ++o) {
            float r = fc2_b[o];
#pragma unroll
            for (int k = 0; k < 64; ++k) r = fmaf(fc2_w[o * 64 + k], z[k], r);
            y[o] = r;
        }
    }
    __syncthreads();
    if (!rev) {
        float* flat = &xch[0][0];
#pragma unroll
        for (int o = 0; o < 20; ++o) flat[s * 20 + o] = y[o];
    }
    __syncthreads();
    {
        const float* flat = &xch[0][0];
        for (int f = tid; f < 128 * 20; f += 256)
            out[(size_t)blockIdx.x * (128 * 20) + f] = flat[f];
    }
}

extern "C" void kernel_launch(void* const* d_in, const int* in_sizes, int n_in,
                              void* d_out, int out_size, void* d_ws, size_t ws_size,
                              hipStream_t stream) {
    const float* x = (const float*)d_in[0];
    // layer 0: 1..4 fwd, 5..8 rev ; layer 1: 9..12 fwd, 13..16 rev
    const float* w_ih_l0  = (const float*)d_in[1];
    const float* w_hh_l0  = (const float*)d_in[2];
    const float* b_ih_l0  = (const float*)d_in[3];
    const float* b_hh_l0  = (const float*)d_in[4];
    const float* w_ih_l0r = (const float*)d_in[5];
    const float* w_hh_l0r = (const float*)d_in[6];
    const float* b_ih_l0r = (const float*)d_in[7];
    const float* b_hh_l0r = (const float*)d_in[8];
    const float* w_ih_l1  = (const float*)d_in[9];
    const float* w_hh_l1  = (const float*)d_in[10];
    const float* b_ih_l1  = (const float*)d_in[11];
    const float* b_hh_l1  = (const float*)d_in[12];
    const float* w_ih_l1r = (const float*)d_in[13];
    const float* w_hh_l1r = (const float*)d_in[14];
    const float* b_ih_l1r = (const float*)d_in[15];
    const float* b_hh_l1r = (const float*)d_in[16];
    const float* fc1_w = (const float*)d_in[17];
    const float* fc1_b = (const float*)d_in[18];
    const float* fc2_w = (const float*)d_in[19];
    const float* fc2_b = (const float*)d_in[20];

    float* h1     = (float*)d_ws;                                  // [100][4][65536] f32 = 104,857,600 B
    float* fc1_wt = (float*)((char*)d_ws + (size_t)Tn * 4 * Bn * sizeof(float));  // [400][64]

    fc1t_kernel<<<100, 256, 0, stream>>>(fc1_w, fc1_wt);
    l0_kernel<<<512, 256, 0, stream>>>(x,
        w_ih_l0, w_hh_l0, b_ih_l0, b_hh_l0,
        w_ih_l0r, w_hh_l0r, b_ih_l0r, b_hh_l0r, h1);
    l1fc_kernel<<<512, 256, 0, stream>>>(h1,
        w_ih_l1, w_hh_l1, b_ih_l1, b_hh_l1,
        w_ih_l1r, w_hh_l1r, b_ih_l1r, b_hh_l1r,
        fc1_wt, fc1_b, fc2_w, fc2_b, (float*)d_out);
}